// Round 3
// baseline (7747.028 us; speedup 1.0000x reference)
//
#include <hip/hip_runtime.h>
#include <stdint.h>

#define T_SEQ   2048
#define DMODEL  1024
#define NHEADS  16
#define HDIM    64
#define BATCH   4
#define MROWS   (BATCH * T_SEQ)   // 8192

// ---------------------------------------------------------------------------
// fp32 GEMM: C[M][N] = A[M][Kd] * B[Kd][N] + bias[N]
// 64x64 tile, BK=32, 256 threads, 4x4 microtile per thread.
// mode 0: epilogue scatters qkv into Q/K/V [B,H,T,HDIM] fp32 buffers
// mode 1: epilogue writes O0[gm*N + gn]
// ---------------------------------------------------------------------------
__global__ __launch_bounds__(256) void gemm_kernel(
    const float* __restrict__ A,
    const float* __restrict__ Bm,
    const float* __restrict__ bias,
    int N, int Kd, int mode,
    float* __restrict__ O0,
    float* __restrict__ O1,
    float* __restrict__ O2)
{
    // k-major LDS tiles: As[k*68 + m], Bs[k*68 + n], padded stride 68
    __shared__ __align__(16) float As[32 * 68];
    __shared__ __align__(16) float Bs[32 * 68];

    const int tid = threadIdx.x;
    const int tx  = tid & 15;    // n direction (4 cols each)
    const int ty  = tid >> 4;    // m direction (4 rows each)
    const int m0  = blockIdx.y * 64;
    const int n0  = blockIdx.x * 64;

    const int arow = tid >> 2;        // 0..63 : m row in tile
    const int akc  = (tid & 3) * 8;   // k chunk of 8
    const int brow = tid >> 3;        // 0..31 : k row in tile
    const int bnc  = (tid & 7) * 8;   // n chunk of 8

    float c[4][4] = {{0.f}};

    for (int k0 = 0; k0 < Kd; k0 += 32) {
        const float4 av0 = *(const float4*)(A + (size_t)(m0 + arow) * Kd + k0 + akc);
        const float4 av1 = *(const float4*)(A + (size_t)(m0 + arow) * Kd + k0 + akc + 4);
        const float4 bv0 = *(const float4*)(Bm + (size_t)(k0 + brow) * N + n0 + bnc);
        const float4 bv1 = *(const float4*)(Bm + (size_t)(k0 + brow) * N + n0 + bnc + 4);

        __syncthreads();  // previous tile fully consumed before overwrite
        {
            const float wa[8] = {av0.x, av0.y, av0.z, av0.w, av1.x, av1.y, av1.z, av1.w};
            #pragma unroll
            for (int i = 0; i < 8; i++) As[(akc + i) * 68 + arow] = wa[i];
            const float wb[8] = {bv0.x, bv0.y, bv0.z, bv0.w, bv1.x, bv1.y, bv1.z, bv1.w};
            #pragma unroll
            for (int i = 0; i < 8; i++) Bs[brow * 68 + bnc + i] = wb[i];
        }
        __syncthreads();

        #pragma unroll
        for (int kk = 0; kk < 32; kk++) {
            const float4 a = *(const float4*)&As[kk * 68 + ty * 4];
            const float4 b = *(const float4*)&Bs[kk * 68 + tx * 4];
            c[0][0] += a.x * b.x; c[0][1] += a.x * b.y; c[0][2] += a.x * b.z; c[0][3] += a.x * b.w;
            c[1][0] += a.y * b.x; c[1][1] += a.y * b.y; c[1][2] += a.y * b.z; c[1][3] += a.y * b.w;
            c[2][0] += a.z * b.x; c[2][1] += a.z * b.y; c[2][2] += a.z * b.z; c[2][3] += a.z * b.w;
            c[3][0] += a.w * b.x; c[3][1] += a.w * b.y; c[3][2] += a.w * b.z; c[3][3] += a.w * b.w;
        }
    }

    if (mode == 0) {
        #pragma unroll
        for (int i = 0; i < 4; i++) {
            const int gm = m0 + ty * 4 + i;
            const int b  = gm >> 11;        // / T_SEQ
            const int t  = gm & 2047;
            #pragma unroll
            for (int j = 0; j < 4; j++) {
                const int gn = n0 + tx * 4 + j;
                const float v = c[i][j] + bias[gn];
                const int which = gn >> 10;     // 0=q 1=k 2=v
                const int rem   = gn & 1023;
                const int h     = rem >> 6;
                const int d     = rem & 63;
                float* dst = (which == 0) ? O0 : ((which == 1) ? O1 : O2);
                const size_t idx = (((size_t)(b * NHEADS + h)) * T_SEQ + t) * HDIM + d;
                dst[idx] = v;
            }
        }
    } else {
        #pragma unroll
        for (int i = 0; i < 4; i++) {
            const int gm = m0 + ty * 4 + i;
            #pragma unroll
            for (int j = 0; j < 4; j++) {
                const int gn = n0 + tx * 4 + j;
                O0[(size_t)gm * N + gn] = c[i][j] + bias[gn];
            }
        }
    }
}

// ---------------------------------------------------------------------------
// Causal flash attention: one wave (64 lanes) per query row. Hd = 64 = wave.
// Q/K/V are fp32 [B*H][T][64]. Output written as [B*T][DMODEL] fp32.
// ---------------------------------------------------------------------------
__global__ __launch_bounds__(256) void attn_kernel(
    const float* __restrict__ Q,
    const float* __restrict__ K,
    const float* __restrict__ V,
    float* __restrict__ Out)
{
    const int lane = threadIdx.x & 63;
    const int w    = threadIdx.x >> 6;
    const int blk  = blockIdx.x;          // 64 bh * 512 row-groups
    const int bh   = blk >> 9;
    const int t    = ((blk & 511) << 2) | w;
    const size_t base = (size_t)bh * T_SEQ * HDIM;

    // broadcast q row into registers, pre-scaled by 1/sqrt(64)
    float q[64];
    {
        const float4* q4 = (const float4*)(Q + base + (size_t)t * HDIM);
        #pragma unroll
        for (int i = 0; i < 16; i++) {
            const float4 u = q4[i];
            q[i * 4 + 0] = u.x * 0.125f;
            q[i * 4 + 1] = u.y * 0.125f;
            q[i * 4 + 2] = u.z * 0.125f;
            q[i * 4 + 3] = u.w * 0.125f;
        }
    }

    float m = -INFINITY, l = 0.f, o = 0.f;

    for (int kb = 0; kb <= t; kb += 64) {
        const int j = kb + lane;
        // score for key j (always in-bounds: kb <= t <= 2047)
        float s = 0.f;
        {
            const float4* k4 = (const float4*)(K + base + (size_t)j * HDIM);
            #pragma unroll
            for (int i = 0; i < 16; i++) {
                const float4 u = k4[i];
                s += q[i * 4 + 0] * u.x;
                s += q[i * 4 + 1] * u.y;
                s += q[i * 4 + 2] * u.z;
                s += q[i * 4 + 3] * u.w;
            }
        }
        if (j > t) s = -INFINITY;   // causal mask

        // online softmax update (wave-uniform m, l after reductions)
        float mc = s;
        #pragma unroll
        for (int off = 32; off > 0; off >>= 1) mc = fmaxf(mc, __shfl_xor(mc, off));
        const float mn    = fmaxf(m, mc);
        const float alpha = __expf(m - mn);     // first iter: exp(-inf) = 0
        const float p     = __expf(s - mn);     // masked lanes: exp(-inf) = 0
        float ps = p;
        #pragma unroll
        for (int off = 32; off > 0; off >>= 1) ps += __shfl_xor(ps, off);
        l = l * alpha + ps;
        m = mn;
        o *= alpha;

        // PV: lane owns output dim d = lane; p_j broadcast via shuffle
        const float* vb = V + base + (size_t)kb * HDIM + lane;
        #pragma unroll
        for (int jj = 0; jj < 64; jj++) {
            const float pj = __shfl(p, jj);
            o += pj * vb[(size_t)jj * HDIM];
        }
    }

    const int b = bh >> 4, h = bh & 15;
    Out[((size_t)(b * T_SEQ + t)) * DMODEL + h * HDIM + lane] = o / l;
}

extern "C" void kernel_launch(void* const* d_in, const int* in_sizes, int n_in,
                              void* d_out, int out_size, void* d_ws, size_t ws_size,
                              hipStream_t stream)
{
    const float* x    = (const float*)d_in[0];
    const float* Wqkv = (const float*)d_in[1];
    const float* bqkv = (const float*)d_in[2];
    const float* Wout = (const float*)d_in[3];
    const float* bout = (const float*)d_in[4];
    float* out = (float*)d_out;

    // workspace layout (fp32): Q | K | V | attn_out  -> 32 MiB each, 128 MiB total
    char* ws = (char*)d_ws;
    float* Qb = (float*)(ws + (size_t)0  * 1024 * 1024);
    float* Kb = (float*)(ws + (size_t)32 * 1024 * 1024);
    float* Vb = (float*)(ws + (size_t)64 * 1024 * 1024);
    float* Ab = (float*)(ws + (size_t)96 * 1024 * 1024);

    // 1) qkv = x @ W_qkv + b_qkv, scattered to Q/K/V [B,H,T,64]
    gemm_kernel<<<dim3(3 * DMODEL / 64, MROWS / 64), 256, 0, stream>>>(
        x, Wqkv, bqkv, 3 * DMODEL, DMODEL, 0, Qb, Kb, Vb);

    // 2) causal attention -> Ab [B*T][DMODEL]
    attn_kernel<<<dim3(BATCH * NHEADS * T_SEQ / 4), 256, 0, stream>>>(Qb, Kb, Vb, Ab);

    // 3) out = Ab @ W_out + b_out
    gemm_kernel<<<dim3(DMODEL / 64, MROWS / 64), 256, 0, stream>>>(
        Ab, Wout, bout, DMODEL, DMODEL, 1, out, nullptr, nullptr);
}

// Round 4
// 1354.593 us; speedup vs baseline: 5.7191x; 5.7191x over previous
//
#include <hip/hip_runtime.h>
#include <stdint.h>

#define T_SEQ   2048
#define DMODEL  1024
#define NHEADS  16
#define HDIM    64
#define BATCH   4
#define MROWS   (BATCH * T_SEQ)   // 8192

typedef __attribute__((ext_vector_type(4))) short bf16x4;
typedef __attribute__((ext_vector_type(8))) short bf16x8;
typedef __attribute__((ext_vector_type(4))) float f32x4;

__device__ __forceinline__ float b2f(unsigned short u) {
    union { unsigned int i; float f; } x;
    x.i = ((unsigned int)u) << 16;
    return x.f;
}

__device__ __forceinline__ unsigned short f2b(float f) {
    union { float f; unsigned int i; } x;
    x.f = f;
    unsigned int r = x.i + 0x7FFFu + ((x.i >> 16) & 1u);  // RNE
    return (unsigned short)(r >> 16);
}

// ---------------------------------------------------------------------------
// fp32 GEMM: C[M][N] = A[M][Kd] * B[Kd][N] + bias[N]
// 64x64 tile, BK=32, 256 threads, 4x4 microtile.
// mode 0: scatter qkv -> Qb (bf16, pre-scaled 1/8) [bh][t][d],
//         Kb (bf16) [bh][t][d], Vt (bf16, transposed) [bh][d][t]
// mode 1: Of[gm*N + gn] = c + bias (fp32)
// ---------------------------------------------------------------------------
__global__ __launch_bounds__(256) void gemm_kernel(
    const float* __restrict__ A,
    const float* __restrict__ Bm,
    const float* __restrict__ bias,
    int N, int Kd, int mode,
    unsigned short* __restrict__ Oq,
    unsigned short* __restrict__ Ok,
    unsigned short* __restrict__ Ov,
    float* __restrict__ Of)
{
    __shared__ __align__(16) float As[32 * 68];
    __shared__ __align__(16) float Bs[32 * 68];

    const int tid = threadIdx.x;
    const int tx  = tid & 15;
    const int ty  = tid >> 4;
    const int m0  = blockIdx.y * 64;
    const int n0  = blockIdx.x * 64;

    const int arow = tid >> 2;
    const int akc  = (tid & 3) * 8;
    const int brow = tid >> 3;
    const int bnc  = (tid & 7) * 8;

    float c[4][4] = {{0.f}};

    for (int k0 = 0; k0 < Kd; k0 += 32) {
        const float4 av0 = *(const float4*)(A + (size_t)(m0 + arow) * Kd + k0 + akc);
        const float4 av1 = *(const float4*)(A + (size_t)(m0 + arow) * Kd + k0 + akc + 4);
        const float4 bv0 = *(const float4*)(Bm + (size_t)(k0 + brow) * N + n0 + bnc);
        const float4 bv1 = *(const float4*)(Bm + (size_t)(k0 + brow) * N + n0 + bnc + 4);

        __syncthreads();
        {
            const float wa[8] = {av0.x, av0.y, av0.z, av0.w, av1.x, av1.y, av1.z, av1.w};
            #pragma unroll
            for (int i = 0; i < 8; i++) As[(akc + i) * 68 + arow] = wa[i];
            const float wb[8] = {bv0.x, bv0.y, bv0.z, bv0.w, bv1.x, bv1.y, bv1.z, bv1.w};
            #pragma unroll
            for (int i = 0; i < 8; i++) Bs[brow * 68 + bnc + i] = wb[i];
        }
        __syncthreads();

        #pragma unroll
        for (int kk = 0; kk < 32; kk++) {
            const float4 a = *(const float4*)&As[kk * 68 + ty * 4];
            const float4 b = *(const float4*)&Bs[kk * 68 + tx * 4];
            c[0][0] += a.x * b.x; c[0][1] += a.x * b.y; c[0][2] += a.x * b.z; c[0][3] += a.x * b.w;
            c[1][0] += a.y * b.x; c[1][1] += a.y * b.y; c[1][2] += a.y * b.z; c[1][3] += a.y * b.w;
            c[2][0] += a.z * b.x; c[2][1] += a.z * b.y; c[2][2] += a.z * b.z; c[2][3] += a.z * b.w;
            c[3][0] += a.w * b.x; c[3][1] += a.w * b.y; c[3][2] += a.w * b.z; c[3][3] += a.w * b.w;
        }
    }

    if (mode == 0) {
        #pragma unroll
        for (int i = 0; i < 4; i++) {
            const int gm = m0 + ty * 4 + i;
            const int b  = gm >> 11;        // / T_SEQ
            const int t  = gm & 2047;
            #pragma unroll
            for (int j = 0; j < 4; j++) {
                const int gn = n0 + tx * 4 + j;
                const float v = c[i][j] + bias[gn];
                const int which = gn >> 10;     // 0=q 1=k 2=v
                const int rem   = gn & 1023;
                const int h     = rem >> 6;
                const int d     = rem & 63;
                const int bh    = b * NHEADS + h;
                if (which == 0) {
                    Oq[((size_t)bh * T_SEQ + t) * HDIM + d] = f2b(v * 0.125f);
                } else if (which == 1) {
                    Ok[((size_t)bh * T_SEQ + t) * HDIM + d] = f2b(v);
                } else {
                    Ov[((size_t)bh * HDIM + d) * T_SEQ + t] = f2b(v);
                }
            }
        }
    } else {
        #pragma unroll
        for (int i = 0; i < 4; i++) {
            const int gm = m0 + ty * 4 + i;
            #pragma unroll
            for (int j = 0; j < 4; j++) {
                const int gn = n0 + tx * 4 + j;
                Of[(size_t)gm * N + gn] = c[i][j] + bias[gn];
            }
        }
    }
}

// ---------------------------------------------------------------------------
// MFMA flash attention, transpose-free.
// Per wave: 16 queries. S^T = K_tile @ Q^T via mfma_f32_16x16x32_bf16
// (C layout: S^T[key=quad*4+r][q=lane&15]) which IS the B-operand layout of
// mfma_f32_16x16x16bf16_1k (B[k=quad*4+j][n=lane&15]) -> P^T feeds
// O^T = V^T @ P^T directly from registers. V pre-transposed [bh][d][T].
// Q pre-scaled by 1/sqrt(64) at production time.
// ---------------------------------------------------------------------------
__global__ __launch_bounds__(256) void attn_mfma(
    const unsigned short* __restrict__ Q,   // [bh][t][64] bf16 (scaled)
    const unsigned short* __restrict__ K,   // [bh][t][64] bf16
    const unsigned short* __restrict__ VT,  // [bh][64][T] bf16
    float* __restrict__ Out)                // [B*T][DMODEL] fp32
{
    const int lane = threadIdx.x & 63;
    const int wave = threadIdx.x >> 6;
    const int row  = lane & 15;   // q (and K-row / V^T-d-row for frag loads)
    const int quad = lane >> 4;

    const int bh = blockIdx.x;
    const int b  = bh >> 4;
    const int h  = bh & 15;
    const int q0 = (blockIdx.y * 4 + wave) * 16;

    const size_t qkbase = (size_t)bh * T_SEQ * HDIM;
    const size_t vtbase = (size_t)bh * HDIM * T_SEQ;

    // Q fragments (held for the whole kernel): Q[q0+row][quad*8 + j (+32)]
    const unsigned short* qp = Q + qkbase + (size_t)(q0 + row) * HDIM + quad * 8;
    const bf16x8 qf0 = *(const bf16x8*)qp;
    const bf16x8 qf1 = *(const bf16x8*)(qp + 32);

    f32x4 o[4] = {{0.f,0.f,0.f,0.f},{0.f,0.f,0.f,0.f},{0.f,0.f,0.f,0.f},{0.f,0.f,0.f,0.f}};
    float m = -1e30f, l = 0.f;

    const int nk = q0 + 16;   // keys [0, nk)
    for (int kb = 0; kb < nk; kb += 16) {
        // K fragments: K[kb+row][quad*8 + j (+32)]
        const unsigned short* kp = K + qkbase + (size_t)(kb + row) * HDIM + quad * 8;
        const bf16x8 kf0 = *(const bf16x8*)kp;
        const bf16x8 kf1 = *(const bf16x8*)(kp + 32);

        f32x4 s4 = {0.f, 0.f, 0.f, 0.f};
        s4 = __builtin_amdgcn_mfma_f32_16x16x32_bf16(kf0, qf0, s4, 0, 0, 0);
        s4 = __builtin_amdgcn_mfma_f32_16x16x32_bf16(kf1, qf1, s4, 0, 0, 0);
        // s4[r] = S^T[key=kb+quad*4+r][q=q0+row]

        if (kb == q0) {   // diagonal subtile: causal mask (wave-uniform branch)
            #pragma unroll
            for (int r = 0; r < 4; r++)
                if (quad * 4 + r > row) s4[r] = -1e30f;
        }

        // online softmax (per-q state in lane q=lane&15, replicated per quad)
        float mc = fmaxf(fmaxf(s4[0], s4[1]), fmaxf(s4[2], s4[3]));
        mc = fmaxf(mc, __shfl_xor(mc, 16));
        mc = fmaxf(mc, __shfl_xor(mc, 32));
        const float mn    = fmaxf(m, mc);
        const float alpha = __expf(m - mn);

        bf16x4 pf;
        float ps = 0.f;
        #pragma unroll
        for (int r = 0; r < 4; r++) {
            const unsigned short pb = f2b(__expf(s4[r] - mn));
            pf[r] = (short)pb;
            ps += b2f(pb);   // l consistent with bf16-rounded P
        }
        ps += __shfl_xor(ps, 16);
        ps += __shfl_xor(ps, 32);
        l = l * alpha + ps;
        m = mn;

        #pragma unroll
        for (int dt = 0; dt < 4; dt++) {
            #pragma unroll
            for (int r = 0; r < 4; r++) o[dt][r] *= alpha;
        }

        // O^T += V^T @ P^T ; A-frag = VT[dt*16+row][kb+quad*4 + j] (8B load)
        #pragma unroll
        for (int dt = 0; dt < 4; dt++) {
            const unsigned short* vp = VT + vtbase + (size_t)(dt * 16 + row) * T_SEQ + kb + quad * 4;
            const bf16x4 vf = *(const bf16x4*)vp;
            o[dt] = __builtin_amdgcn_mfma_f32_16x16x16bf16_1k(vf, pf, o[dt], 0, 0, 0);
        }
    }

    const float rl = 1.f / l;
    // lane holds O^T[d=dt*16+quad*4+r][q=q0+row]
    float* op = Out + ((size_t)(b * T_SEQ + q0 + row)) * DMODEL + h * HDIM;
    #pragma unroll
    for (int dt = 0; dt < 4; dt++) {
        #pragma unroll
        for (int r = 0; r < 4; r++)
            op[dt * 16 + quad * 4 + r] = o[dt][r] * rl;
    }
}

extern "C" void kernel_launch(void* const* d_in, const int* in_sizes, int n_in,
                              void* d_out, int out_size, void* d_ws, size_t ws_size,
                              hipStream_t stream)
{
    const float* x    = (const float*)d_in[0];
    const float* Wqkv = (const float*)d_in[1];
    const float* bqkv = (const float*)d_in[2];
    const float* Wout = (const float*)d_in[3];
    const float* bout = (const float*)d_in[4];
    float* out = (float*)d_out;

    // workspace: Qb/Kb/Vt bf16 16 MiB each, Ab fp32 32 MiB -> 80 MiB total
    char* ws = (char*)d_ws;
    unsigned short* Qb = (unsigned short*)(ws + (size_t)0  * 1024 * 1024);
    unsigned short* Kb = (unsigned short*)(ws + (size_t)16 * 1024 * 1024);
    unsigned short* Vt = (unsigned short*)(ws + (size_t)32 * 1024 * 1024);
    float*          Ab = (float*)         (ws + (size_t)48 * 1024 * 1024);

    // 1) qkv = x @ W_qkv + b_qkv -> bf16 Q (scaled), K, V^T
    gemm_kernel<<<dim3(3 * DMODEL / 64, MROWS / 64), 256, 0, stream>>>(
        x, Wqkv, bqkv, 3 * DMODEL, DMODEL, 0, Qb, Kb, Vt, nullptr);

    // 2) causal MFMA flash attention -> Ab [B*T][DMODEL] fp32
    attn_mfma<<<dim3(BATCH * NHEADS, T_SEQ / 64), 256, 0, stream>>>(Qb, Kb, Vt, Ab);

    // 3) out = Ab @ W_out + b_out
    gemm_kernel<<<dim3(DMODEL / 64, MROWS / 64), 256, 0, stream>>>(
        Ab, Wout, bout, DMODEL, DMODEL, 1, nullptr, nullptr, nullptr, out);
}

// Round 5
// 606.801 us; speedup vs baseline: 12.7670x; 2.2324x over previous
//
#include <hip/hip_runtime.h>
#include <stdint.h>

#define T_SEQ   2048
#define DMODEL  1024
#define NHEADS  16
#define HDIM    64
#define BATCH   4
#define MROWS   (BATCH * T_SEQ)   // 8192

typedef __attribute__((ext_vector_type(4))) short bf16x4;
typedef __attribute__((ext_vector_type(8))) short bf16x8;
typedef __attribute__((ext_vector_type(4))) float f32x4;

__device__ __forceinline__ float b2f(unsigned short u) {
    union { unsigned int i; float f; } x;
    x.i = ((unsigned int)u) << 16;
    return x.f;
}

__device__ __forceinline__ unsigned short f2b(float f) {
    union { float f; unsigned int i; } x;
    x.f = f;
    unsigned int r = x.i + 0x7FFFu + ((x.i >> 16) & 1u);  // RNE
    return (unsigned short)(r >> 16);
}

// ---------------------------------------------------------------------------
// fp32 -> bf16 elementwise convert
// ---------------------------------------------------------------------------
__global__ __launch_bounds__(256) void cvt_bf16(
    const float* __restrict__ in, unsigned short* __restrict__ out, int n)
{
    const int i = (blockIdx.x * 256 + threadIdx.x) * 4;
    if (i + 3 < n) {
        const float4 v = *(const float4*)(in + i);
        ushort4 o;
        o.x = f2b(v.x); o.y = f2b(v.y); o.z = f2b(v.z); o.w = f2b(v.w);
        *(ushort4*)(out + i) = o;
    }
}

// ---------------------------------------------------------------------------
// fp32 [K][N] -> bf16 [N][K] transpose+convert, 32x32 LDS tile
// ---------------------------------------------------------------------------
__global__ __launch_bounds__(256) void cvt_tr(
    const float* __restrict__ W, unsigned short* __restrict__ WT, int K, int N)
{
    __shared__ unsigned short s[32][33];
    const int n0 = blockIdx.x * 32, k0 = blockIdx.y * 32;
    const int tx = threadIdx.x & 31, ty = threadIdx.x >> 5;   // ty 0..7
    #pragma unroll
    for (int i = 0; i < 4; i++)
        s[ty + 8 * i][tx] = f2b(W[(size_t)(k0 + ty + 8 * i) * N + n0 + tx]);
    __syncthreads();
    #pragma unroll
    for (int i = 0; i < 4; i++)
        WT[(size_t)(n0 + ty + 8 * i) * K + k0 + tx] = s[tx][ty + 8 * i];
}

// ---------------------------------------------------------------------------
// bf16 MFMA GEMM: C[M][N] = A[M][Kd] * BT[N][Kd]^T + bias[N]
// 128x128 tile, BK=32, 256 thr = 4 waves (2x2), each wave 64x64 = 4x4 MFMAs.
// LDS frag-contiguous with swizzled k-slot: chunk (sub, row, kq) at
//   elem offset sub*512 + row*32 + ((kq + (row>>1))&3)*8
// -> staging stores sequential-ish (conflict-free), frag ds_read_b128 2-way.
// mode 0: scatter qkv -> Qb (bf16, ×0.125) [bh][t][d], Kb [bh][t][d],
//         Vt [bh][d][t]
// mode 1: Of[m*N+n] = c + bias (fp32)
// ---------------------------------------------------------------------------
__global__ __launch_bounds__(256) void gemm_mfma(
    const unsigned short* __restrict__ A,
    const unsigned short* __restrict__ BT,
    const float* __restrict__ bias,
    int N, int Kd, int mode,
    unsigned short* __restrict__ Oq,
    unsigned short* __restrict__ Ok,
    unsigned short* __restrict__ Ov,
    float* __restrict__ Of)
{
    __shared__ __align__(16) unsigned short aS[128 * 32];
    __shared__ __align__(16) unsigned short bS[128 * 32];

    const int tid  = threadIdx.x;
    const int lane = tid & 63;
    const int wave = tid >> 6;
    const int row  = lane & 15;
    const int quad = lane >> 4;
    const int wm   = wave >> 1;
    const int wn   = wave & 1;
    const int m0   = blockIdx.y * 128;
    const int n0   = blockIdx.x * 128;

    // staging role: lane -> (srow = lane>>2, kq = lane&3); wave handles
    // subtiles (wave) and (wave+4) for both A and B.
    const int srow  = lane >> 2;
    const int kq    = lane & 3;
    const int sslot = (kq + (srow >> 1)) & 3;
    const int soffA = wave * 512 + srow * 32 + sslot * 8;          // elems
    // frag read offset within a subtile block (elems)
    const int frd = row * 32 + (((quad + (row >> 1)) & 3) * 8);

    f32x4 acc[4][4];
    const f32x4 z = {0.f, 0.f, 0.f, 0.f};
    #pragma unroll
    for (int i = 0; i < 4; i++)
        #pragma unroll
        for (int j = 0; j < 4; j++) acc[i][j] = z;

    for (int k0 = 0; k0 < Kd; k0 += 32) {
        const uint4 a0 = *(const uint4*)(A  + (size_t)(m0 + wave * 16      + srow) * Kd + k0 + kq * 8);
        const uint4 a1 = *(const uint4*)(A  + (size_t)(m0 + (wave + 4) * 16 + srow) * Kd + k0 + kq * 8);
        const uint4 b0 = *(const uint4*)(BT + (size_t)(n0 + wave * 16      + srow) * Kd + k0 + kq * 8);
        const uint4 b1 = *(const uint4*)(BT + (size_t)(n0 + (wave + 4) * 16 + srow) * Kd + k0 + kq * 8);

        __syncthreads();   // all waves done reading previous tile
        *(uint4*)(aS + soffA)        = a0;
        *(uint4*)(aS + soffA + 2048) = a1;   // (wave+4)*512 = wave*512 + 2048
        *(uint4*)(bS + soffA)        = b0;
        *(uint4*)(bS + soffA + 2048) = b1;
        __syncthreads();

        bf16x8 af[4], bf[4];
        #pragma unroll
        for (int t = 0; t < 4; t++) {
            af[t] = *(const bf16x8*)(aS + (wm * 4 + t) * 512 + frd);
            bf[t] = *(const bf16x8*)(bS + (wn * 4 + t) * 512 + frd);
        }
        #pragma unroll
        for (int i = 0; i < 4; i++)
            #pragma unroll
            for (int j = 0; j < 4; j++)
                acc[i][j] = __builtin_amdgcn_mfma_f32_16x16x32_bf16(af[i], bf[j], acc[i][j], 0, 0, 0);
    }

    // epilogue: acc[i][j][r] -> (m = m0+wm*64+i*16+quad*4+r, n = n0+wn*64+j*16+row)
    if (mode == 0) {
        #pragma unroll
        for (int j = 0; j < 4; j++) {
            const int n  = n0 + wn * 64 + j * 16 + row;
            const float bi = bias[n];
            const int which = n >> 10;
            const int rem   = n & 1023;
            const int h     = rem >> 6;
            const int d     = rem & 63;
            #pragma unroll
            for (int i = 0; i < 4; i++) {
                const int mbase = m0 + wm * 64 + i * 16 + quad * 4;
                #pragma unroll
                for (int r = 0; r < 4; r++) {
                    const int m = mbase + r;
                    const int b = m >> 11;
                    const int t = m & 2047;
                    const int bh = b * NHEADS + h;
                    const float v = acc[i][j][r] + bi;
                    if (which == 0) {
                        Oq[((size_t)bh * T_SEQ + t) * HDIM + d] = f2b(v * 0.125f);
                    } else if (which == 1) {
                        Ok[((size_t)bh * T_SEQ + t) * HDIM + d] = f2b(v);
                    } else {
                        Ov[((size_t)bh * HDIM + d) * T_SEQ + t] = f2b(v);
                    }
                }
            }
        }
    } else {
        #pragma unroll
        for (int j = 0; j < 4; j++) {
            const int n  = n0 + wn * 64 + j * 16 + row;
            const float bi = bias[n];
            #pragma unroll
            for (int i = 0; i < 4; i++) {
                const int mbase = m0 + wm * 64 + i * 16 + quad * 4;
                #pragma unroll
                for (int r = 0; r < 4; r++)
                    Of[(size_t)(mbase + r) * N + n] = acc[i][j][r] + bi;
            }
        }
    }
}

// ---------------------------------------------------------------------------
// MFMA flash attention (R4-verified), output now bf16 packed 8B stores.
// ---------------------------------------------------------------------------
__global__ __launch_bounds__(256) void attn_mfma(
    const unsigned short* __restrict__ Q,   // [bh][t][64] bf16 (scaled)
    const unsigned short* __restrict__ K,   // [bh][t][64] bf16
    const unsigned short* __restrict__ VT,  // [bh][64][T] bf16
    unsigned short* __restrict__ Out)       // [B*T][DMODEL] bf16
{
    const int lane = threadIdx.x & 63;
    const int wave = threadIdx.x >> 6;
    const int row  = lane & 15;
    const int quad = lane >> 4;

    const int bh = blockIdx.x;
    const int b  = bh >> 4;
    const int h  = bh & 15;
    const int q0 = (blockIdx.y * 4 + wave) * 16;

    const size_t qkbase = (size_t)bh * T_SEQ * HDIM;
    const size_t vtbase = (size_t)bh * HDIM * T_SEQ;

    const unsigned short* qp = Q + qkbase + (size_t)(q0 + row) * HDIM + quad * 8;
    const bf16x8 qf0 = *(const bf16x8*)qp;
    const bf16x8 qf1 = *(const bf16x8*)(qp + 32);

    f32x4 o[4] = {{0.f,0.f,0.f,0.f},{0.f,0.f,0.f,0.f},{0.f,0.f,0.f,0.f},{0.f,0.f,0.f,0.f}};
    float m = -1e30f, l = 0.f;

    const int nk = q0 + 16;
    for (int kb = 0; kb < nk; kb += 16) {
        const unsigned short* kp = K + qkbase + (size_t)(kb + row) * HDIM + quad * 8;
        const bf16x8 kf0 = *(const bf16x8*)kp;
        const bf16x8 kf1 = *(const bf16x8*)(kp + 32);

        f32x4 s4 = {0.f, 0.f, 0.f, 0.f};
        s4 = __builtin_amdgcn_mfma_f32_16x16x32_bf16(kf0, qf0, s4, 0, 0, 0);
        s4 = __builtin_amdgcn_mfma_f32_16x16x32_bf16(kf1, qf1, s4, 0, 0, 0);

        if (kb == q0) {
            #pragma unroll
            for (int r = 0; r < 4; r++)
                if (quad * 4 + r > row) s4[r] = -1e30f;
        }

        float mc = fmaxf(fmaxf(s4[0], s4[1]), fmaxf(s4[2], s4[3]));
        mc = fmaxf(mc, __shfl_xor(mc, 16));
        mc = fmaxf(mc, __shfl_xor(mc, 32));
        const float mn    = fmaxf(m, mc);
        const float alpha = __expf(m - mn);

        bf16x4 pf;
        float ps = 0.f;
        #pragma unroll
        for (int r = 0; r < 4; r++) {
            const unsigned short pb = f2b(__expf(s4[r] - mn));
            pf[r] = (short)pb;
            ps += b2f(pb);
        }
        ps += __shfl_xor(ps, 16);
        ps += __shfl_xor(ps, 32);
        l = l * alpha + ps;
        m = mn;

        #pragma unroll
        for (int dt = 0; dt < 4; dt++) {
            #pragma unroll
            for (int r = 0; r < 4; r++) o[dt][r] *= alpha;
        }

        #pragma unroll
        for (int dt = 0; dt < 4; dt++) {
            const unsigned short* vp = VT + vtbase + (size_t)(dt * 16 + row) * T_SEQ + kb + quad * 4;
            const bf16x4 vf = *(const bf16x4*)vp;
            o[dt] = __builtin_amdgcn_mfma_f32_16x16x16bf16_1k(vf, pf, o[dt], 0, 0, 0);
        }
    }

    const float rl = 1.f / l;
    // lane holds O^T[d = dt*16 + quad*4 + r][q = q0+row]; pack 4 d's -> 8B store
    unsigned short* op = Out + ((size_t)(b * T_SEQ + q0 + row)) * DMODEL + h * HDIM + quad * 4;
    #pragma unroll
    for (int dt = 0; dt < 4; dt++) {
        ushort4 pk;
        pk.x = f2b(o[dt][0] * rl);
        pk.y = f2b(o[dt][1] * rl);
        pk.z = f2b(o[dt][2] * rl);
        pk.w = f2b(o[dt][3] * rl);
        *(ushort4*)(op + dt * 16) = pk;
    }
}

extern "C" void kernel_launch(void* const* d_in, const int* in_sizes, int n_in,
                              void* d_out, int out_size, void* d_ws, size_t ws_size,
                              hipStream_t stream)
{
    const float* x    = (const float*)d_in[0];
    const float* Wqkv = (const float*)d_in[1];
    const float* bqkv = (const float*)d_in[2];
    const float* Wout = (const float*)d_in[3];
    const float* bout = (const float*)d_in[4];
    float* out = (float*)d_out;

    // workspace (MiB offsets): xb 0..16 | WqkvT 16..22 | WoutT 22..24 |
    // Qb 24..40 | Kb 40..56 | Vt 56..72 | Ab 72..88
    char* ws = (char*)d_ws;
    unsigned short* xb    = (unsigned short*)(ws + (size_t)0  * 1024 * 1024);
    unsigned short* WqkvT = (unsigned short*)(ws + (size_t)16 * 1024 * 1024);
    unsigned short* WoutT = (unsigned short*)(ws + (size_t)22 * 1024 * 1024);
    unsigned short* Qb    = (unsigned short*)(ws + (size_t)24 * 1024 * 1024);
    unsigned short* Kb    = (unsigned short*)(ws + (size_t)40 * 1024 * 1024);
    unsigned short* Vt    = (unsigned short*)(ws + (size_t)56 * 1024 * 1024);
    unsigned short* Ab    = (unsigned short*)(ws + (size_t)72 * 1024 * 1024);

    // 0) converts / transposes
    cvt_bf16<<<dim3(MROWS * DMODEL / 1024), 256, 0, stream>>>(x, xb, MROWS * DMODEL);
    cvt_tr<<<dim3(3 * DMODEL / 32, DMODEL / 32), 256, 0, stream>>>(Wqkv, WqkvT, DMODEL, 3 * DMODEL);
    cvt_tr<<<dim3(DMODEL / 32, DMODEL / 32), 256, 0, stream>>>(Wout, WoutT, DMODEL, DMODEL);

    // 1) qkv = x @ W_qkv + b_qkv -> Qb (scaled), Kb, Vt
    gemm_mfma<<<dim3(3 * DMODEL / 128, MROWS / 128), 256, 0, stream>>>(
        xb, WqkvT, bqkv, 3 * DMODEL, DMODEL, 0, Qb, Kb, Vt, nullptr);

    // 2) causal MFMA flash attention -> Ab bf16
    attn_mfma<<<dim3(BATCH * NHEADS, T_SEQ / 64), 256, 0, stream>>>(Qb, Kb, Vt, Ab);

    // 3) out = Ab @ W_out + b_out (fp32 out)
    gemm_mfma<<<dim3(DMODEL / 128, MROWS / 128), 256, 0, stream>>>(
        Ab, WoutT, bout, DMODEL, DMODEL, 1, nullptr, nullptr, nullptr, out);
}

// Round 6
// 587.586 us; speedup vs baseline: 13.1845x; 1.0327x over previous
//
#include <hip/hip_runtime.h>
#include <stdint.h>

#define T_SEQ   2048
#define DMODEL  1024
#define NHEADS  16
#define HDIM    64
#define BATCH   4
#define MROWS   (BATCH * T_SEQ)   // 8192

typedef __attribute__((ext_vector_type(4))) short bf16x4;
typedef __attribute__((ext_vector_type(8))) short bf16x8;
typedef __attribute__((ext_vector_type(4))) float f32x4;

__device__ __forceinline__ float b2f(unsigned short u) {
    union { unsigned int i; float f; } x;
    x.i = ((unsigned int)u) << 16;
    return x.f;
}

__device__ __forceinline__ unsigned short f2b(float f) {
    union { float f; unsigned int i; } x;
    x.f = f;
    unsigned int r = x.i + 0x7FFFu + ((x.i >> 16) & 1u);  // RNE
    return (unsigned short)(r >> 16);
}

// ---------------------------------------------------------------------------
// fp32 -> bf16 elementwise convert
// ---------------------------------------------------------------------------
__global__ __launch_bounds__(256) void cvt_bf16(
    const float* __restrict__ in, unsigned short* __restrict__ out, int n)
{
    const int i = (blockIdx.x * 256 + threadIdx.x) * 4;
    if (i + 3 < n) {
        const float4 v = *(const float4*)(in + i);
        ushort4 o;
        o.x = f2b(v.x); o.y = f2b(v.y); o.z = f2b(v.z); o.w = f2b(v.w);
        *(ushort4*)(out + i) = o;
    }
}

// ---------------------------------------------------------------------------
// fp32 [K][N] -> bf16 [N][K] transpose+convert, 32x32 LDS tile
// ---------------------------------------------------------------------------
__global__ __launch_bounds__(256) void cvt_tr(
    const float* __restrict__ W, unsigned short* __restrict__ WT, int K, int N)
{
    __shared__ unsigned short s[32][33];
    const int n0 = blockIdx.x * 32, k0 = blockIdx.y * 32;
    const int tx = threadIdx.x & 31, ty = threadIdx.x >> 5;   // ty 0..7
    #pragma unroll
    for (int i = 0; i < 4; i++)
        s[ty + 8 * i][tx] = f2b(W[(size_t)(k0 + ty + 8 * i) * N + n0 + tx]);
    __syncthreads();
    #pragma unroll
    for (int i = 0; i < 4; i++)
        WT[(size_t)(n0 + ty + 8 * i) * K + k0 + tx] = s[tx][ty + 8 * i];
}

// ---------------------------------------------------------------------------
// bf16 MFMA GEMM: C[M][N] = A[M][Kd] * BT[N][Kd]^T + bias[N]
// 128x128 tile, BK=32, 256 thr = 4 waves (2x2), each wave 64x64 = 4x4 MFMAs.
// (unchanged from R5)
// ---------------------------------------------------------------------------
__global__ __launch_bounds__(256) void gemm_mfma(
    const unsigned short* __restrict__ A,
    const unsigned short* __restrict__ BT,
    const float* __restrict__ bias,
    int N, int Kd, int mode,
    unsigned short* __restrict__ Oq,
    unsigned short* __restrict__ Ok,
    unsigned short* __restrict__ Ov,
    float* __restrict__ Of)
{
    __shared__ __align__(16) unsigned short aS[128 * 32];
    __shared__ __align__(16) unsigned short bS[128 * 32];

    const int tid  = threadIdx.x;
    const int lane = tid & 63;
    const int wave = tid >> 6;
    const int row  = lane & 15;
    const int quad = lane >> 4;
    const int wm   = wave >> 1;
    const int wn   = wave & 1;
    const int m0   = blockIdx.y * 128;
    const int n0   = blockIdx.x * 128;

    const int srow  = lane >> 2;
    const int kq    = lane & 3;
    const int sslot = (kq + (srow >> 1)) & 3;
    const int soffA = wave * 512 + srow * 32 + sslot * 8;
    const int frd = row * 32 + (((quad + (row >> 1)) & 3) * 8);

    f32x4 acc[4][4];
    const f32x4 z = {0.f, 0.f, 0.f, 0.f};
    #pragma unroll
    for (int i = 0; i < 4; i++)
        #pragma unroll
        for (int j = 0; j < 4; j++) acc[i][j] = z;

    for (int k0 = 0; k0 < Kd; k0 += 32) {
        const uint4 a0 = *(const uint4*)(A  + (size_t)(m0 + wave * 16      + srow) * Kd + k0 + kq * 8);
        const uint4 a1 = *(const uint4*)(A  + (size_t)(m0 + (wave + 4) * 16 + srow) * Kd + k0 + kq * 8);
        const uint4 b0 = *(const uint4*)(BT + (size_t)(n0 + wave * 16      + srow) * Kd + k0 + kq * 8);
        const uint4 b1 = *(const uint4*)(BT + (size_t)(n0 + (wave + 4) * 16 + srow) * Kd + k0 + kq * 8);

        __syncthreads();
        *(uint4*)(aS + soffA)        = a0;
        *(uint4*)(aS + soffA + 2048) = a1;
        *(uint4*)(bS + soffA)        = b0;
        *(uint4*)(bS + soffA + 2048) = b1;
        __syncthreads();

        bf16x8 af[4], bf[4];
        #pragma unroll
        for (int t = 0; t < 4; t++) {
            af[t] = *(const bf16x8*)(aS + (wm * 4 + t) * 512 + frd);
            bf[t] = *(const bf16x8*)(bS + (wn * 4 + t) * 512 + frd);
        }
        #pragma unroll
        for (int i = 0; i < 4; i++)
            #pragma unroll
            for (int j = 0; j < 4; j++)
                acc[i][j] = __builtin_amdgcn_mfma_f32_16x16x32_bf16(af[i], bf[j], acc[i][j], 0, 0, 0);
    }

    if (mode == 0) {
        #pragma unroll
        for (int j = 0; j < 4; j++) {
            const int n  = n0 + wn * 64 + j * 16 + row;
            const float bi = bias[n];
            const int which = n >> 10;
            const int rem   = n & 1023;
            const int h     = rem >> 6;
            const int d     = rem & 63;
            #pragma unroll
            for (int i = 0; i < 4; i++) {
                const int mbase = m0 + wm * 64 + i * 16 + quad * 4;
                #pragma unroll
                for (int r = 0; r < 4; r++) {
                    const int m = mbase + r;
                    const int b = m >> 11;
                    const int t = m & 2047;
                    const int bh = b * NHEADS + h;
                    const float v = acc[i][j][r] + bi;
                    if (which == 0) {
                        Oq[((size_t)bh * T_SEQ + t) * HDIM + d] = f2b(v * 0.125f);
                    } else if (which == 1) {
                        Ok[((size_t)bh * T_SEQ + t) * HDIM + d] = f2b(v);
                    } else {
                        Ov[((size_t)bh * HDIM + d) * T_SEQ + t] = f2b(v);
                    }
                }
            }
        }
    } else {
        #pragma unroll
        for (int j = 0; j < 4; j++) {
            const int n  = n0 + wn * 64 + j * 16 + row;
            const float bi = bias[n];
            #pragma unroll
            for (int i = 0; i < 4; i++) {
                const int mbase = m0 + wm * 64 + i * 16 + quad * 4;
                #pragma unroll
                for (int r = 0; r < 4; r++)
                    Of[(size_t)(mbase + r) * N + n] = acc[i][j][r] + bi;
            }
        }
    }
}

// ---------------------------------------------------------------------------
// MFMA flash attention, 64-key blocks per online-softmax update.
// Per wave: 16 queries. S^T = K @ Q^T (C layout = 1k B-operand layout),
// P^T feeds O^T = V^T @ P^T from registers. One softmax chain + one
// accumulator rescale per 64 keys (was per 16). Heavy q-tiles dispatch first.
// ---------------------------------------------------------------------------
__global__ __launch_bounds__(256) void attn_mfma(
    const unsigned short* __restrict__ Q,   // [bh][t][64] bf16 (scaled)
    const unsigned short* __restrict__ K,   // [bh][t][64] bf16
    const unsigned short* __restrict__ VT,  // [bh][64][T] bf16
    unsigned short* __restrict__ Out)       // [B*T][DMODEL] bf16
{
    const int lane = threadIdx.x & 63;
    const int wave = threadIdx.x >> 6;
    const int row  = lane & 15;
    const int quad = lane >> 4;

    const int bh = blockIdx.x;
    const int b  = bh >> 4;
    const int h  = bh & 15;
    const int qg = gridDim.y - 1 - blockIdx.y;   // heavy tiles first
    const int q0 = (qg * 4 + wave) * 16;

    const size_t qkbase = (size_t)bh * T_SEQ * HDIM;
    const size_t vtbase = (size_t)bh * HDIM * T_SEQ;

    const unsigned short* qp = Q + qkbase + (size_t)(q0 + row) * HDIM + quad * 8;
    const bf16x8 qf0 = *(const bf16x8*)qp;
    const bf16x8 qf1 = *(const bf16x8*)(qp + 32);

    f32x4 o[4] = {{0.f,0.f,0.f,0.f},{0.f,0.f,0.f,0.f},{0.f,0.f,0.f,0.f},{0.f,0.f,0.f,0.f}};
    float m = -1e30f, l = 0.f;

    const int kend = q0 + 16;   // keys [0, kend)
    for (int kb = 0; kb < kend; kb += 64) {
        // ---- QK^T for 4 subtiles (keys kb+16s .. kb+16s+15) ----
        f32x4 s4[4];
        #pragma unroll
        for (int s = 0; s < 4; s++) {
            const unsigned short* kp = K + qkbase + (size_t)(kb + s * 16 + row) * HDIM + quad * 8;
            const bf16x8 kf0 = *(const bf16x8*)kp;
            const bf16x8 kf1 = *(const bf16x8*)(kp + 32);
            f32x4 t = {0.f, 0.f, 0.f, 0.f};
            t = __builtin_amdgcn_mfma_f32_16x16x32_bf16(kf0, qf0, t, 0, 0, 0);
            t = __builtin_amdgcn_mfma_f32_16x16x32_bf16(kf1, qf1, t, 0, 0, 0);
            s4[s] = t;
        }

        // ---- causal mask ----
        #pragma unroll
        for (int s = 0; s < 4; s++) {
            const int kbs = kb + s * 16;
            if (kbs > q0) {                 // fully above diagonal (uniform)
                #pragma unroll
                for (int r = 0; r < 4; r++) s4[s][r] = -1e30f;
            } else if (kbs == q0) {         // diagonal subtile
                #pragma unroll
                for (int r = 0; r < 4; r++)
                    if (quad * 4 + r > row) s4[s][r] = -1e30f;
            }
        }

        // ---- one online-softmax update for all 64 keys ----
        float mc = -1e30f;
        #pragma unroll
        for (int s = 0; s < 4; s++)
            #pragma unroll
            for (int r = 0; r < 4; r++) mc = fmaxf(mc, s4[s][r]);
        mc = fmaxf(mc, __shfl_xor(mc, 16));
        mc = fmaxf(mc, __shfl_xor(mc, 32));
        const float mn    = fmaxf(m, mc);
        const float alpha = __expf(m - mn);

        bf16x4 pf[4];
        float ps = 0.f;
        #pragma unroll
        for (int s = 0; s < 4; s++) {
            #pragma unroll
            for (int r = 0; r < 4; r++) {
                const unsigned short pb = f2b(__expf(s4[s][r] - mn));
                pf[s][r] = (short)pb;
                ps += b2f(pb);
            }
        }
        ps += __shfl_xor(ps, 16);
        ps += __shfl_xor(ps, 32);
        l = l * alpha + ps;
        m = mn;

        #pragma unroll
        for (int dt = 0; dt < 4; dt++) {
            #pragma unroll
            for (int r = 0; r < 4; r++) o[dt][r] *= alpha;
        }

        // ---- O^T += V^T @ P^T over 4 subtiles ----
        #pragma unroll
        for (int s = 0; s < 4; s++) {
            #pragma unroll
            for (int dt = 0; dt < 4; dt++) {
                const unsigned short* vp = VT + vtbase + (size_t)(dt * 16 + row) * T_SEQ + kb + s * 16 + quad * 4;
                const bf16x4 vf = *(const bf16x4*)vp;
                o[dt] = __builtin_amdgcn_mfma_f32_16x16x16bf16_1k(vf, pf[s], o[dt], 0, 0, 0);
            }
        }
    }

    const float rl = 1.f / l;
    unsigned short* op = Out + ((size_t)(b * T_SEQ + q0 + row)) * DMODEL + h * HDIM + quad * 4;
    #pragma unroll
    for (int dt = 0; dt < 4; dt++) {
        ushort4 pk;
        pk.x = f2b(o[dt][0] * rl);
        pk.y = f2b(o[dt][1] * rl);
        pk.z = f2b(o[dt][2] * rl);
        pk.w = f2b(o[dt][3] * rl);
        *(ushort4*)(op + dt * 16) = pk;
    }
}

extern "C" void kernel_launch(void* const* d_in, const int* in_sizes, int n_in,
                              void* d_out, int out_size, void* d_ws, size_t ws_size,
                              hipStream_t stream)
{
    const float* x    = (const float*)d_in[0];
    const float* Wqkv = (const float*)d_in[1];
    const float* bqkv = (const float*)d_in[2];
    const float* Wout = (const float*)d_in[3];
    const float* bout = (const float*)d_in[4];
    float* out = (float*)d_out;

    // workspace (MiB offsets): xb 0..16 | WqkvT 16..22 | WoutT 22..24 |
    // Qb 24..40 | Kb 40..56 | Vt 56..72 | Ab 72..88
    char* ws = (char*)d_ws;
    unsigned short* xb    = (unsigned short*)(ws + (size_t)0  * 1024 * 1024);
    unsigned short* WqkvT = (unsigned short*)(ws + (size_t)16 * 1024 * 1024);
    unsigned short* WoutT = (unsigned short*)(ws + (size_t)22 * 1024 * 1024);
    unsigned short* Qb    = (unsigned short*)(ws + (size_t)24 * 1024 * 1024);
    unsigned short* Kb    = (unsigned short*)(ws + (size_t)40 * 1024 * 1024);
    unsigned short* Vt    = (unsigned short*)(ws + (size_t)56 * 1024 * 1024);
    unsigned short* Ab    = (unsigned short*)(ws + (size_t)72 * 1024 * 1024);

    // 0) converts / transposes
    cvt_bf16<<<dim3(MROWS * DMODEL / 1024), 256, 0, stream>>>(x, xb, MROWS * DMODEL);
    cvt_tr<<<dim3(3 * DMODEL / 32, DMODEL / 32), 256, 0, stream>>>(Wqkv, WqkvT, DMODEL, 3 * DMODEL);
    cvt_tr<<<dim3(DMODEL / 32, DMODEL / 32), 256, 0, stream>>>(Wout, WoutT, DMODEL, DMODEL);

    // 1) qkv = x @ W_qkv + b_qkv -> Qb (scaled), Kb, Vt
    gemm_mfma<<<dim3(3 * DMODEL / 128, MROWS / 128), 256, 0, stream>>>(
        xb, WqkvT, bqkv, 3 * DMODEL, DMODEL, 0, Qb, Kb, Vt, nullptr);

    // 2) causal MFMA flash attention -> Ab bf16
    attn_mfma<<<dim3(BATCH * NHEADS, T_SEQ / 64), 256, 0, stream>>>(Qb, Kb, Vt, Ab);

    // 3) out = Ab @ W_out + b_out (fp32 out)
    gemm_mfma<<<dim3(DMODEL / 128, MROWS / 128), 256, 0, stream>>>(
        Ab, WoutT, bout, DMODEL, DMODEL, 1, nullptr, nullptr, nullptr, out);
}

// Round 7
// 549.463 us; speedup vs baseline: 14.0993x; 1.0694x over previous
//
#include <hip/hip_runtime.h>
#include <stdint.h>

#define T_SEQ   2048
#define DMODEL  1024
#define NHEADS  16
#define HDIM    64
#define BATCH   4
#define MROWS   (BATCH * T_SEQ)   // 8192

typedef __attribute__((ext_vector_type(4))) short bf16x4;
typedef __attribute__((ext_vector_type(8))) short bf16x8;
typedef __attribute__((ext_vector_type(4))) float f32x4;

__device__ __forceinline__ float b2f(unsigned short u) {
    union { unsigned int i; float f; } x;
    x.i = ((unsigned int)u) << 16;
    return x.f;
}

__device__ __forceinline__ unsigned short f2b(float f) {
    union { float f; unsigned int i; } x;
    x.f = f;
    unsigned int r = x.i + 0x7FFFu + ((x.i >> 16) & 1u);  // RNE
    return (unsigned short)(r >> 16);
}

// ---------------------------------------------------------------------------
// fp32 -> bf16 elementwise convert
// ---------------------------------------------------------------------------
__global__ __launch_bounds__(256) void cvt_bf16(
    const float* __restrict__ in, unsigned short* __restrict__ out, int n)
{
    const int i = (blockIdx.x * 256 + threadIdx.x) * 4;
    if (i + 3 < n) {
        const float4 v = *(const float4*)(in + i);
        ushort4 o;
        o.x = f2b(v.x); o.y = f2b(v.y); o.z = f2b(v.z); o.w = f2b(v.w);
        *(ushort4*)(out + i) = o;
    }
}

// ---------------------------------------------------------------------------
// fp32 [K][N] -> bf16 [N][K] transpose+convert, 32x32 LDS tile
// ---------------------------------------------------------------------------
__global__ __launch_bounds__(256) void cvt_tr(
    const float* __restrict__ W, unsigned short* __restrict__ WT, int K, int N)
{
    __shared__ unsigned short s[32][33];
    const int n0 = blockIdx.x * 32, k0 = blockIdx.y * 32;
    const int tx = threadIdx.x & 31, ty = threadIdx.x >> 5;   // ty 0..7
    #pragma unroll
    for (int i = 0; i < 4; i++)
        s[ty + 8 * i][tx] = f2b(W[(size_t)(k0 + ty + 8 * i) * N + n0 + tx]);
    __syncthreads();
    #pragma unroll
    for (int i = 0; i < 4; i++)
        WT[(size_t)(n0 + ty + 8 * i) * K + k0 + tx] = s[tx][ty + 8 * i];
}

// ---------------------------------------------------------------------------
// bf16 MFMA GEMM: C[M][N] = A[M][Kd] * BT[N][Kd]^T + bias[N]
// 128x128 tile, BK=32, 256 thr = 4 waves (2x2), each wave 64x64 = 4x4 MFMAs.
// (unchanged from R5)
// ---------------------------------------------------------------------------
__global__ __launch_bounds__(256) void gemm_mfma(
    const unsigned short* __restrict__ A,
    const unsigned short* __restrict__ BT,
    const float* __restrict__ bias,
    int N, int Kd, int mode,
    unsigned short* __restrict__ Oq,
    unsigned short* __restrict__ Ok,
    unsigned short* __restrict__ Ov,
    float* __restrict__ Of)
{
    __shared__ __align__(16) unsigned short aS[128 * 32];
    __shared__ __align__(16) unsigned short bS[128 * 32];

    const int tid  = threadIdx.x;
    const int lane = tid & 63;
    const int wave = tid >> 6;
    const int row  = lane & 15;
    const int quad = lane >> 4;
    const int wm   = wave >> 1;
    const int wn   = wave & 1;
    const int m0   = blockIdx.y * 128;
    const int n0   = blockIdx.x * 128;

    const int srow  = lane >> 2;
    const int kq    = lane & 3;
    const int sslot = (kq + (srow >> 1)) & 3;
    const int soffA = wave * 512 + srow * 32 + sslot * 8;
    const int frd = row * 32 + (((quad + (row >> 1)) & 3) * 8);

    f32x4 acc[4][4];
    const f32x4 z = {0.f, 0.f, 0.f, 0.f};
    #pragma unroll
    for (int i = 0; i < 4; i++)
        #pragma unroll
        for (int j = 0; j < 4; j++) acc[i][j] = z;

    for (int k0 = 0; k0 < Kd; k0 += 32) {
        const uint4 a0 = *(const uint4*)(A  + (size_t)(m0 + wave * 16      + srow) * Kd + k0 + kq * 8);
        const uint4 a1 = *(const uint4*)(A  + (size_t)(m0 + (wave + 4) * 16 + srow) * Kd + k0 + kq * 8);
        const uint4 b0 = *(const uint4*)(BT + (size_t)(n0 + wave * 16      + srow) * Kd + k0 + kq * 8);
        const uint4 b1 = *(const uint4*)(BT + (size_t)(n0 + (wave + 4) * 16 + srow) * Kd + k0 + kq * 8);

        __syncthreads();
        *(uint4*)(aS + soffA)        = a0;
        *(uint4*)(aS + soffA + 2048) = a1;
        *(uint4*)(bS + soffA)        = b0;
        *(uint4*)(bS + soffA + 2048) = b1;
        __syncthreads();

        bf16x8 af[4], bf[4];
        #pragma unroll
        for (int t = 0; t < 4; t++) {
            af[t] = *(const bf16x8*)(aS + (wm * 4 + t) * 512 + frd);
            bf[t] = *(const bf16x8*)(bS + (wn * 4 + t) * 512 + frd);
        }
        #pragma unroll
        for (int i = 0; i < 4; i++)
            #pragma unroll
            for (int j = 0; j < 4; j++)
                acc[i][j] = __builtin_amdgcn_mfma_f32_16x16x32_bf16(af[i], bf[j], acc[i][j], 0, 0, 0);
    }

    if (mode == 0) {
        #pragma unroll
        for (int j = 0; j < 4; j++) {
            const int n  = n0 + wn * 64 + j * 16 + row;
            const float bi = bias[n];
            const int which = n >> 10;
            const int rem   = n & 1023;
            const int h     = rem >> 6;
            const int d     = rem & 63;
            #pragma unroll
            for (int i = 0; i < 4; i++) {
                const int mbase = m0 + wm * 64 + i * 16 + quad * 4;
                #pragma unroll
                for (int r = 0; r < 4; r++) {
                    const int m = mbase + r;
                    const int b = m >> 11;
                    const int t = m & 2047;
                    const int bh = b * NHEADS + h;
                    const float v = acc[i][j][r] + bi;
                    if (which == 0) {
                        Oq[((size_t)bh * T_SEQ + t) * HDIM + d] = f2b(v * 0.125f);
                    } else if (which == 1) {
                        Ok[((size_t)bh * T_SEQ + t) * HDIM + d] = f2b(v);
                    } else {
                        Ov[((size_t)bh * HDIM + d) * T_SEQ + t] = f2b(v);
                    }
                }
            }
        }
    } else {
        #pragma unroll
        for (int j = 0; j < 4; j++) {
            const int n  = n0 + wn * 64 + j * 16 + row;
            const float bi = bias[n];
            #pragma unroll
            for (int i = 0; i < 4; i++) {
                const int mbase = m0 + wm * 64 + i * 16 + quad * 4;
                #pragma unroll
                for (int r = 0; r < 4; r++)
                    Of[(size_t)(mbase + r) * N + n] = acc[i][j][r] + bi;
            }
        }
    }
}

// ---------------------------------------------------------------------------
// MFMA flash attention, balanced dual-tile waves.
// Each wave owns q-tile pair (p, 127-p) of the same bh -> every wave does an
// identical number of 64-key blocks (perfect static balance; grid 1024 wg =
// 4/CU uniform). K and V fragments are loaded once per block and feed both
// tiles' MFMAs; two independent softmax/accum chains give in-wave ILP.
// ---------------------------------------------------------------------------
__global__ __launch_bounds__(256) void attn_mfma(
    const unsigned short* __restrict__ Q,   // [bh][t][64] bf16 (scaled)
    const unsigned short* __restrict__ K,   // [bh][t][64] bf16
    const unsigned short* __restrict__ VT,  // [bh][64][T] bf16
    unsigned short* __restrict__ Out)       // [B*T][DMODEL] bf16
{
    const int lane = threadIdx.x & 63;
    const int wave = threadIdx.x >> 6;
    const int row  = lane & 15;
    const int quad = lane >> 4;

    const int bh = blockIdx.x;
    const int b  = bh >> 4;
    const int h  = bh & 15;
    const int p  = blockIdx.y * 4 + wave;     // 0..63
    const int q0L = 16 * p;
    const int q0H = 16 * (127 - p);

    const size_t qkbase = (size_t)bh * T_SEQ * HDIM;
    const size_t vtbase = (size_t)bh * HDIM * T_SEQ;

    const unsigned short* qpL = Q + qkbase + (size_t)(q0L + row) * HDIM + quad * 8;
    const bf16x8 qL0 = *(const bf16x8*)qpL;
    const bf16x8 qL1 = *(const bf16x8*)(qpL + 32);
    const unsigned short* qpH = Q + qkbase + (size_t)(q0H + row) * HDIM + quad * 8;
    const bf16x8 qH0 = *(const bf16x8*)qpH;
    const bf16x8 qH1 = *(const bf16x8*)(qpH + 32);

    const f32x4 z = {0.f, 0.f, 0.f, 0.f};
    f32x4 oL[4] = {z, z, z, z};
    f32x4 oH[4] = {z, z, z, z};
    float mL = -1e30f, lL = 0.f, mH = -1e30f, lH = 0.f;

    const int kendL = q0L + 16;
    const int kendH = q0H + 16;

    for (int kb = 0; kb < kendH; kb += 64) {
        const bool doL = (kb < kendL);     // wave-uniform

        // ---- QK^T for both tiles, K frags loaded once ----
        f32x4 sH[4], sL[4];
        #pragma unroll
        for (int s = 0; s < 4; s++) {
            const unsigned short* kp = K + qkbase + (size_t)(kb + s * 16 + row) * HDIM + quad * 8;
            const bf16x8 kf0 = *(const bf16x8*)kp;
            const bf16x8 kf1 = *(const bf16x8*)(kp + 32);
            f32x4 t = z;
            t = __builtin_amdgcn_mfma_f32_16x16x32_bf16(kf0, qH0, t, 0, 0, 0);
            t = __builtin_amdgcn_mfma_f32_16x16x32_bf16(kf1, qH1, t, 0, 0, 0);
            sH[s] = t;
            if (doL) {
                f32x4 u = z;
                u = __builtin_amdgcn_mfma_f32_16x16x32_bf16(kf0, qL0, u, 0, 0, 0);
                u = __builtin_amdgcn_mfma_f32_16x16x32_bf16(kf1, qL1, u, 0, 0, 0);
                sL[s] = u;
            }
        }

        // ---- causal masks ----
        #pragma unroll
        for (int s = 0; s < 4; s++) {
            const int kbs = kb + s * 16;
            if (kbs > q0H) {
                #pragma unroll
                for (int r = 0; r < 4; r++) sH[s][r] = -1e30f;
            } else if (kbs == q0H) {
                #pragma unroll
                for (int r = 0; r < 4; r++)
                    if (quad * 4 + r > row) sH[s][r] = -1e30f;
            }
        }
        if (doL) {
            #pragma unroll
            for (int s = 0; s < 4; s++) {
                const int kbs = kb + s * 16;
                if (kbs > q0L) {
                    #pragma unroll
                    for (int r = 0; r < 4; r++) sL[s][r] = -1e30f;
                } else if (kbs == q0L) {
                    #pragma unroll
                    for (int r = 0; r < 4; r++)
                        if (quad * 4 + r > row) sL[s][r] = -1e30f;
                }
            }
        }

        // ---- online softmax, tile H ----
        bf16x4 pfH[4];
        {
            float mc = -1e30f;
            #pragma unroll
            for (int s = 0; s < 4; s++)
                #pragma unroll
                for (int r = 0; r < 4; r++) mc = fmaxf(mc, sH[s][r]);
            mc = fmaxf(mc, __shfl_xor(mc, 16));
            mc = fmaxf(mc, __shfl_xor(mc, 32));
            const float mn    = fmaxf(mH, mc);
            const float alpha = __expf(mH - mn);
            float ps = 0.f;
            #pragma unroll
            for (int s = 0; s < 4; s++) {
                #pragma unroll
                for (int r = 0; r < 4; r++) {
                    const unsigned short pb = f2b(__expf(sH[s][r] - mn));
                    pfH[s][r] = (short)pb;
                    ps += b2f(pb);
                }
            }
            ps += __shfl_xor(ps, 16);
            ps += __shfl_xor(ps, 32);
            lH = lH * alpha + ps;
            mH = mn;
            #pragma unroll
            for (int dt = 0; dt < 4; dt++)
                #pragma unroll
                for (int r = 0; r < 4; r++) oH[dt][r] *= alpha;
        }

        // ---- online softmax, tile L ----
        bf16x4 pfL[4];
        if (doL) {
            float mc = -1e30f;
            #pragma unroll
            for (int s = 0; s < 4; s++)
                #pragma unroll
                for (int r = 0; r < 4; r++) mc = fmaxf(mc, sL[s][r]);
            mc = fmaxf(mc, __shfl_xor(mc, 16));
            mc = fmaxf(mc, __shfl_xor(mc, 32));
            const float mn    = fmaxf(mL, mc);
            const float alpha = __expf(mL - mn);
            float ps = 0.f;
            #pragma unroll
            for (int s = 0; s < 4; s++) {
                #pragma unroll
                for (int r = 0; r < 4; r++) {
                    const unsigned short pb = f2b(__expf(sL[s][r] - mn));
                    pfL[s][r] = (short)pb;
                    ps += b2f(pb);
                }
            }
            ps += __shfl_xor(ps, 16);
            ps += __shfl_xor(ps, 32);
            lL = lL * alpha + ps;
            mL = mn;
            #pragma unroll
            for (int dt = 0; dt < 4; dt++)
                #pragma unroll
                for (int r = 0; r < 4; r++) oL[dt][r] *= alpha;
        }

        // ---- PV for both tiles, V frags loaded once ----
        #pragma unroll
        for (int s = 0; s < 4; s++) {
            #pragma unroll
            for (int dt = 0; dt < 4; dt++) {
                const unsigned short* vp = VT + vtbase + (size_t)(dt * 16 + row) * T_SEQ + kb + s * 16 + quad * 4;
                const bf16x4 vf = *(const bf16x4*)vp;
                oH[dt] = __builtin_amdgcn_mfma_f32_16x16x16bf16_1k(vf, pfH[s], oH[dt], 0, 0, 0);
                if (doL)
                    oL[dt] = __builtin_amdgcn_mfma_f32_16x16x16bf16_1k(vf, pfL[s], oL[dt], 0, 0, 0);
            }
        }
    }

    // ---- epilogue: both tiles ----
    {
        const float rl = 1.f / lH;
        unsigned short* op = Out + ((size_t)(b * T_SEQ + q0H + row)) * DMODEL + h * HDIM + quad * 4;
        #pragma unroll
        for (int dt = 0; dt < 4; dt++) {
            ushort4 pk;
            pk.x = f2b(oH[dt][0] * rl);
            pk.y = f2b(oH[dt][1] * rl);
            pk.z = f2b(oH[dt][2] * rl);
            pk.w = f2b(oH[dt][3] * rl);
            *(ushort4*)(op + dt * 16) = pk;
        }
    }
    {
        const float rl = 1.f / lL;
        unsigned short* op = Out + ((size_t)(b * T_SEQ + q0L + row)) * DMODEL + h * HDIM + quad * 4;
        #pragma unroll
        for (int dt = 0; dt < 4; dt++) {
            ushort4 pk;
            pk.x = f2b(oL[dt][0] * rl);
            pk.y = f2b(oL[dt][1] * rl);
            pk.z = f2b(oL[dt][2] * rl);
            pk.w = f2b(oL[dt][3] * rl);
            *(ushort4*)(op + dt * 16) = pk;
        }
    }
}

extern "C" void kernel_launch(void* const* d_in, const int* in_sizes, int n_in,
                              void* d_out, int out_size, void* d_ws, size_t ws_size,
                              hipStream_t stream)
{
    const float* x    = (const float*)d_in[0];
    const float* Wqkv = (const float*)d_in[1];
    const float* bqkv = (const float*)d_in[2];
    const float* Wout = (const float*)d_in[3];
    const float* bout = (const float*)d_in[4];
    float* out = (float*)d_out;

    // workspace (MiB offsets): xb 0..16 | WqkvT 16..22 | WoutT 22..24 |
    // Qb 24..40 | Kb 40..56 | Vt 56..72 | Ab 72..88
    char* ws = (char*)d_ws;
    unsigned short* xb    = (unsigned short*)(ws + (size_t)0  * 1024 * 1024);
    unsigned short* WqkvT = (unsigned short*)(ws + (size_t)16 * 1024 * 1024);
    unsigned short* WoutT = (unsigned short*)(ws + (size_t)22 * 1024 * 1024);
    unsigned short* Qb    = (unsigned short*)(ws + (size_t)24 * 1024 * 1024);
    unsigned short* Kb    = (unsigned short*)(ws + (size_t)40 * 1024 * 1024);
    unsigned short* Vt    = (unsigned short*)(ws + (size_t)56 * 1024 * 1024);
    unsigned short* Ab    = (unsigned short*)(ws + (size_t)72 * 1024 * 1024);

    // 0) converts / transposes
    cvt_bf16<<<dim3(MROWS * DMODEL / 1024), 256, 0, stream>>>(x, xb, MROWS * DMODEL);
    cvt_tr<<<dim3(3 * DMODEL / 32, DMODEL / 32), 256, 0, stream>>>(Wqkv, WqkvT, DMODEL, 3 * DMODEL);
    cvt_tr<<<dim3(DMODEL / 32, DMODEL / 32), 256, 0, stream>>>(Wout, WoutT, DMODEL, DMODEL);

    // 1) qkv = x @ W_qkv + b_qkv -> Qb (scaled), Kb, Vt
    gemm_mfma<<<dim3(3 * DMODEL / 128, MROWS / 128), 256, 0, stream>>>(
        xb, WqkvT, bqkv, 3 * DMODEL, DMODEL, 0, Qb, Kb, Vt, nullptr);

    // 2) causal MFMA flash attention (balanced pairs) -> Ab bf16
    attn_mfma<<<dim3(BATCH * NHEADS, 16), 256, 0, stream>>>(Qb, Kb, Vt, Ab);

    // 3) out = Ab @ W_out + b_out (fp32 out)
    gemm_mfma<<<dim3(DMODEL / 128, MROWS / 128), 256, 0, stream>>>(
        Ab, WoutT, bout, DMODEL, DMODEL, 1, nullptr, nullptr, nullptr, out);
}